// Round 1
// baseline (209.778 us; speedup 1.0000x reference)
//
#include <hip/hip_runtime.h>
#include <hip/hip_bf16.h>

#define D 128
#define K 64

typedef __attribute__((ext_vector_type(8))) short short8;   // 8 bf16 in 4 VGPRs
typedef __attribute__((ext_vector_type(4))) float f32x4;

// round-to-nearest-even float -> bf16 bits (inputs are finite, no NaN handling needed)
__device__ inline short f2bf(float f) {
  union { float f; unsigned u; } v; v.f = f;
  unsigned u = v.u;
  return (short)((u + 0x7fffu + ((u >> 16) & 1u)) >> 16);
}

// ws layout (floats): [0..16) accumulator slots; [16..80) mnorm[64]; [128..) bf16(2*m) as 8192 shorts
__global__ void prep_kernel(const float* __restrict__ m, float* ws) {
  int tid = threadIdx.x;
  if (tid < 16) ws[tid] = 0.0f;
  if (tid < K) {
    const float* mr = m + tid * D;
    float s = 0.f;
    for (int d = 0; d < D; ++d) s += mr[d] * mr[d];
    ws[16 + tid] = s;
  }
  short* mb = (short*)(ws + 128);
  for (int i = tid; i < K * D; i += blockDim.x) mb[i] = f2bf(2.0f * m[i]);
}

__launch_bounds__(256)
__global__ void main_kernel(const float* __restrict__ x, float* ws, int nTiles, int totalWaves) {
  const float* mnorm = ws + 16;
  const short* mb = (const short*)(ws + 128);
  const int lane = threadIdx.x & 63;
  const int lid  = lane & 15;   // A: M row / B: N col / C/D: col (j)
  const int quad = lane >> 4;   // k-element group; C/D row = quad*4+reg

  // All of m lives in registers per wave: 4 j-tiles x 4 k-steps, 4 VGPRs each.
  short8 bfr[4][4];
  float mn[4];
#pragma unroll
  for (int jt = 0; jt < 4; ++jt) {
    mn[jt] = mnorm[jt * 16 + lid];
#pragma unroll
    for (int kk = 0; kk < 4; ++kk)
      bfr[jt][kk] = *(const short8*)(mb + (jt * 16 + lid) * D + kk * 32 + quad * 8);
  }

  const int wave = blockIdx.x * (blockDim.x >> 6) + (threadIdx.x >> 6);
  float hacc = 0.f;

  for (int t = wave; t < nTiles; t += totalWaves) {
    const float* xb = x + (size_t)(t * 16 + lid) * D + quad * 8;
    short8 a[4];
#pragma unroll
    for (int kk = 0; kk < 4; ++kk) {
      f32x4 v0 = *(const f32x4*)(xb + kk * 32);
      f32x4 v1 = *(const f32x4*)(xb + kk * 32 + 4);
      short8 av;
      av[0] = f2bf(v0[0]); av[1] = f2bf(v0[1]); av[2] = f2bf(v0[2]); av[3] = f2bf(v0[3]);
      av[4] = f2bf(v1[0]); av[5] = f2bf(v1[1]); av[6] = f2bf(v1[2]); av[7] = f2bf(v1[3]);
      a[kk] = av;
    }

    f32x4 acc[4];
#pragma unroll
    for (int jt = 0; jt < 4; ++jt) acc[jt] = (f32x4){0.f, 0.f, 0.f, 0.f};
#pragma unroll
    for (int kk = 0; kk < 4; ++kk)
#pragma unroll
      for (int jt = 0; jt < 4; ++jt)
        acc[jt] = __builtin_amdgcn_mfma_f32_16x16x32_bf16(a[kk], bfr[jt][kk], acc[jt], 0, 0, 0);

    // Epilogue: row r (= tile row quad*4+r) has its 64 scores spread as
    // 4 jt-regs here x 16 lanes (lane&15). Butterfly-allreduce over lid.
#pragma unroll
    for (int r = 0; r < 4; ++r) {
      float s0 = acc[0][r] - mn[0];
      float s1 = acc[1][r] - mn[1];
      float s2 = acc[2][r] - mn[2];
      float s3 = acc[3][r] - mn[3];
      float mx = fmaxf(fmaxf(s0, s1), fmaxf(s2, s3));
      for (int off = 1; off < 16; off <<= 1) mx = fmaxf(mx, __shfl_xor(mx, off, 64));
      float t0 = s0 - mx, t1 = s1 - mx, t2 = s2 - mx, t3 = s3 - mx;
      float e0 = __expf(t0), e1 = __expf(t1), e2 = __expf(t2), e3 = __expf(t3);
      float S0 = (e0 + e1) + (e2 + e3);
      float S1 = (t0 * e0 + t1 * e1) + (t2 * e2 + t3 * e3);
      for (int off = 1; off < 16; off <<= 1) {
        S0 += __shfl_xor(S0, off, 64);
        S1 += __shfl_xor(S1, off, 64);
      }
      // H = ln(sum e^t) - sum(t e^t)/sum(e^t); uniform check: ln 64 ✓
      float H = __logf(S0) - S1 / S0;
      if (lid == 0) hacc += H;  // one lane per quad-group owns rows quad*4+r
    }
  }

  // wave reduce then block reduce then one atomic per block
  for (int off = 1; off < 64; off <<= 1) hacc += __shfl_xor(hacc, off, 64);
  __shared__ float red[4];
  if (lane == 0) red[threadIdx.x >> 6] = hacc;
  __syncthreads();
  if (threadIdx.x == 0) atomicAdd(ws, red[0] + red[1] + red[2] + red[3]);
}

__global__ void final_kernel(const float* __restrict__ m, const float* ws, float* out, int nRows) {
  __shared__ float mu[D];
  int lane = threadIdx.x;  // 64 threads
  for (int d = lane; d < D; d += 64) {
    float s = 0.f;
    for (int j = 0; j < K; ++j) s += m[j * D + d];
    mu[d] = s * (1.0f / K);
  }
  __syncthreads();
  const float* mr = m + lane * D;
  float dot = 0.f;
  for (int d = 0; d < D; ++d) dot += mu[d] * mr[d];
  float s = 2.f * dot - ws[16 + lane];  // shift-invariant: drop ||mu||^2
  float mx = s;
  for (int off = 1; off < 64; off <<= 1) mx = fmaxf(mx, __shfl_xor(mx, off, 64));
  float t = s - mx;
  float e = __expf(t);
  float S0 = e, S1 = t * e;
  for (int off = 1; off < 64; off <<= 1) {
    S0 += __shfl_xor(S0, off, 64);
    S1 += __shfl_xor(S1, off, 64);
  }
  float inter = __logf(S0) - S1 / S0;
  if (lane == 0) {
    float intra = ws[0] / (float)nRows;
    out[0] = intra - inter;  // LAMB = 1
    out[1] = intra;
    out[2] = inter;
  }
}

extern "C" void kernel_launch(void* const* d_in, const int* in_sizes, int n_in,
                              void* d_out, int out_size, void* d_ws, size_t ws_size,
                              hipStream_t stream) {
  const float* x = (const float*)d_in[0];
  const float* m = (const float*)d_in[1];
  float* ws = (float*)d_ws;
  float* out = (float*)d_out;
  const int N = in_sizes[0] / D;   // 262144
  const int nTiles = N / 16;       // 16384

  prep_kernel<<<1, 256, 0, stream>>>(m, ws);

  const int blocks = 1024;                  // 4 blocks/CU, 16 waves/CU
  const int totalWaves = blocks * 4;        // 4 tiles per wave
  main_kernel<<<blocks, 256, 0, stream>>>(x, ws, nTiles, totalWaves);

  final_kernel<<<1, 64, 0, stream>>>(m, ws, out, N);
}